// Round 1
// baseline (225.310 us; speedup 1.0000x reference)
//
#include <hip/hip_runtime.h>
#include <stdint.h>

// Problem constants: B=2, S=2048, D=1024, H=16, HD=64
typedef unsigned short u16;
typedef unsigned int u32;
typedef __attribute__((ext_vector_type(8))) short bf16x8;   // 8 bf16 = 4 VGPR
typedef __attribute__((ext_vector_type(4))) float f32x4;

#define MFMA16(a, b, c) __builtin_amdgcn_mfma_f32_16x16x32_bf16((a), (b), (c), 0, 0, 0)

__device__ __forceinline__ u16 f2bf(float f) {  // round-to-nearest-even f32->bf16
  u32 u = __float_as_uint(f);
  u += 0x7fffu + ((u >> 16) & 1u);
  return (u16)(u >> 16);
}

// XOR swizzles (bijective within each row) to spread ds_read_b128 across banks.
// [128][32]-elem tiles: 64B rows, 4x16B chunks. read/write pattern -> 2-way (free).
__device__ __forceinline__ int swz4(int row, int cb) {
  return row * 64 + ((cb ^ ((row >> 1) & 3)) << 4);
}
// [64][64] / [16][64]-elem tiles: 128B rows, 8x16B chunks.
__device__ __forceinline__ int swz8(int row, int cb) {
  return row * 128 + ((cb ^ (row & 7)) << 4);
}

// ---------------------------------------------------------------- cast x -> bf16
__global__ void cast_x_kernel(const float4* __restrict__ in, ushort4* __restrict__ out, int n4) {
  for (int i = blockIdx.x * blockDim.x + threadIdx.x; i < n4; i += gridDim.x * blockDim.x) {
    float4 v = in[i];
    ushort4 o;
    o.x = f2bf(v.x); o.y = f2bf(v.y); o.z = f2bf(v.z); o.w = f2bf(v.w);
    out[i] = o;
  }
}

// ------------------------------------------------- transpose-cast W (D x D) -> W^T bf16
__global__ void transpose_cast_kernel(const float* __restrict__ W0, const float* __restrict__ W1,
                                      const float* __restrict__ W2, const float* __restrict__ W3,
                                      u16* __restrict__ out) {
  const float* W = (blockIdx.z == 0) ? W0 : (blockIdx.z == 1) ? W1 : (blockIdx.z == 2) ? W2 : W3;
  u16* o = out + (size_t)blockIdx.z * 1048576;
  __shared__ float t[32][33];
  int tx = threadIdx.x, ty = threadIdx.y;           // (32, 8)
  int bx = blockIdx.x * 32, by = blockIdx.y * 32;
#pragma unroll
  for (int j = 0; j < 32; j += 8) t[ty + j][tx] = W[(size_t)(by + ty + j) * 1024 + bx + tx];
  __syncthreads();
#pragma unroll
  for (int j = 0; j < 32; j += 8) o[(size_t)(bx + ty + j) * 1024 + by + tx] = f2bf(t[tx][ty + j]);
}

// ------------------------------------------------------------- mask -> bitmask
// MB word layout: MB[(b*2048 + sq)*64 + w] holds bits for k = w*32 .. w*32+31
__global__ void maskbits_kernel(const int* __restrict__ mask, u32* __restrict__ MB) {
  int tid = blockIdx.x * blockDim.x + threadIdx.x;
  int wid = tid >> 6, lane = tid & 63;
  int nw = (gridDim.x * blockDim.x) >> 6;
  for (int c = wid; c < 131072; c += nw) {               // B*S*S/64 chunks
    size_t base = ((size_t)(c >> 5)) * 2048 + (size_t)(c & 31) * 64;
    int v = mask[base + lane];
    unsigned long long bal = __ballot(v != 0);
    if (lane == 0) {
      MB[(size_t)c * 2]     = (u32)bal;
      MB[(size_t)c * 2 + 1] = (u32)(bal >> 32);
    }
  }
}

// ------------------------------------------------------------------ GEMM 128x128
// C(M x 1024) = A(M x 1024) @ B, with B supplied TRANSPOSED (Bt: n-major, k contiguous).
// MODE 0: out bf16 at (b,h,s,hd)      [Q, K]
// MODE 1: out bf16 at (b,h,hd,s)      [V transposed]
// MODE 2: out f32 row-major + bias    [final projection]
template <int MODE>
__global__ __launch_bounds__(256) void gemm128_kernel(const u16* __restrict__ A,
                                                      const u16* __restrict__ Bt,
                                                      void* __restrict__ outp,
                                                      const float* __restrict__ bias) {
  __shared__ u16 As[128 * 32];
  __shared__ u16 Bs[128 * 32];
  const int tid = threadIdx.x;
  const int lane = tid & 63;
  const int l15 = lane & 15, g = lane >> 4;
  const int wave = tid >> 6;
  const int wr = wave >> 1, wc = wave & 1;
  const int m0 = blockIdx.x * 128, n0 = blockIdx.y * 128;
  const int r0 = tid >> 2, cb0 = tid & 3;       // staging coords, pass0: rows 0..63
  const int r1 = 64 + r0;                       // pass1: rows 64..127
  const char* Ab = (const char*)A;
  const char* Bb = (const char*)Bt;
  char* Asc = (char*)As;
  char* Bsc = (char*)Bs;

  f32x4 acc[4][4] = {};

  for (int kt = 0; kt < 32; ++kt) {
    const int kbyte = kt * 64;
    // global loads hoisted above the barrier (overlap with previous compute)
    bf16x8 ga0 = *(const bf16x8*)(Ab + (size_t)(m0 + r0) * 2048 + kbyte + cb0 * 16);
    bf16x8 ga1 = *(const bf16x8*)(Ab + (size_t)(m0 + r1) * 2048 + kbyte + cb0 * 16);
    bf16x8 gb0 = *(const bf16x8*)(Bb + (size_t)(n0 + r0) * 2048 + kbyte + cb0 * 16);
    bf16x8 gb1 = *(const bf16x8*)(Bb + (size_t)(n0 + r1) * 2048 + kbyte + cb0 * 16);
    __syncthreads();   // previous iteration's LDS reads done
    *(bf16x8*)(Asc + swz4(r0, cb0)) = ga0;
    *(bf16x8*)(Asc + swz4(r1, cb0)) = ga1;
    *(bf16x8*)(Bsc + swz4(r0, cb0)) = gb0;
    *(bf16x8*)(Bsc + swz4(r1, cb0)) = gb1;
    __syncthreads();

    bf16x8 af[4], bfr[4];
#pragma unroll
    for (int i = 0; i < 4; ++i)
      af[i] = *(const bf16x8*)(Asc + swz4(wr * 64 + i * 16 + l15, g));
#pragma unroll
    for (int j = 0; j < 4; ++j)
      bfr[j] = *(const bf16x8*)(Bsc + swz4(wc * 64 + j * 16 + l15, g));
#pragma unroll
    for (int i = 0; i < 4; ++i)
#pragma unroll
      for (int j = 0; j < 4; ++j)
        acc[i][j] = MFMA16(af[i], bfr[j], acc[i][j]);
  }

  // epilogue. C frag: col = lane&15, row = (lane>>4)*4 + r  (guide §3, m89/m91 verified)
#pragma unroll
  for (int i = 0; i < 4; ++i) {
    const int mrow = m0 + wr * 64 + i * 16 + g * 4;
#pragma unroll
    for (int j = 0; j < 4; ++j) {
      const int col = n0 + wc * 64 + j * 16 + l15;
      f32x4 v = acc[i][j];
#pragma unroll
      for (int r = 0; r < 4; ++r) {
        const int m = mrow + r;
        if (MODE == 2) {
          ((float*)outp)[(size_t)m * 1024 + col] = v[r] + bias[col];
        } else {
          const int bb = m >> 11, s = m & 2047;
          const int h = col >> 6, hd = col & 63;
          u16 val = f2bf(v[r]);
          if (MODE == 0)
            ((u16*)outp)[(((size_t)(bb * 16 + h)) * 2048 + s) * 64 + hd] = val;
          else
            ((u16*)outp)[(((size_t)(bb * 16 + h)) * 64 + hd) * 2048 + s] = val;
        }
      }
    }
  }
}

// ---------------------------------------------------------------- flash attention
// grid (32 q-blocks, 32 bh). 256 thr = 4 waves, each wave owns 16 q-rows.
// Q: (bh, s, hd) bf16;  K: (bh, s, hd) bf16;  VT: (bh, hd, s) bf16;  CTX out: (b*s, h*hd) bf16
__global__ __launch_bounds__(256) void attn_kernel(const u16* __restrict__ Q,
                                                   const u16* __restrict__ K,
                                                   const u16* __restrict__ VT,
                                                   const u32* __restrict__ MB,
                                                   u16* __restrict__ CTX) {
  __shared__ u16 Kl[64 * 64];
  __shared__ u16 Vl[64 * 64];
  __shared__ u16 Pl[4][16 * 64];
  __shared__ u32 Ml[64][2];
  const int tid = threadIdx.x, lane = tid & 63, wave = tid >> 6;
  const int l15 = lane & 15, g = lane >> 4;
  const int qb = blockIdx.x, bh = blockIdx.y;
  const int b = bh >> 4, h = bh & 15;
  const int q0 = qb * 64;

  // per-wave Q fragments (A operand): row = lane&15, k = (lane>>4)*8 (+32 per kstep)
  const char* Qb = (const char*)(Q + ((size_t)bh * 2048 + q0 + wave * 16) * 64);
  bf16x8 aq0 = *(const bf16x8*)(Qb + l15 * 128 + g * 16);
  bf16x8 aq1 = *(const bf16x8*)(Qb + l15 * 128 + 64 + g * 16);

  const char* Kb = (const char*)(K + (size_t)bh * 2048 * 64);
  const char* Vb = (const char*)(VT + (size_t)bh * 64 * 2048);
  char* Klc = (char*)Kl;
  char* Vlc = (char*)Vl;

  f32x4 oacc[4] = {};
  float mrow[4] = {-3e38f, -3e38f, -3e38f, -3e38f};
  float lrow[4] = {0.f, 0.f, 0.f, 0.f};

  const int sr = tid >> 3, scb = tid & 7;   // staging: rows 0..31 (pass adds 32)

  for (int kb = 0; kb < 32; ++kb) {
    // global loads before the barrier
    bf16x8 k0 = *(const bf16x8*)(Kb + (size_t)(kb * 64 + sr) * 128 + scb * 16);
    bf16x8 k1 = *(const bf16x8*)(Kb + (size_t)(kb * 64 + 32 + sr) * 128 + scb * 16);
    bf16x8 v0 = *(const bf16x8*)(Vb + (size_t)sr * 4096 + kb * 128 + scb * 16);
    bf16x8 v1 = *(const bf16x8*)(Vb + (size_t)(32 + sr) * 4096 + kb * 128 + scb * 16);
    u32 mw = (tid < 128) ? MB[((size_t)b * 2048 + q0 + (tid >> 1)) * 64 + kb * 2 + (tid & 1)] : 0u;
    __syncthreads();   // previous iteration's K/V reads done
    *(bf16x8*)(Klc + swz8(sr, scb)) = k0;
    *(bf16x8*)(Klc + swz8(32 + sr, scb)) = k1;
    *(bf16x8*)(Vlc + swz8(sr, scb)) = v0;
    *(bf16x8*)(Vlc + swz8(32 + sr, scb)) = v1;
    if (tid < 128) Ml[tid >> 1][tid & 1] = mw;
    __syncthreads();

    // ---- QK^T: scores frag i covers k-cols i*16..i*16+15
    f32x4 sacc[4] = {};
#pragma unroll
    for (int i = 0; i < 4; ++i) {
      const int krow = i * 16 + l15;
      bf16x8 bk0 = *(const bf16x8*)(Klc + swz8(krow, g));
      sacc[i] = MFMA16(aq0, bk0, sacc[i]);
      bf16x8 bk1 = *(const bf16x8*)(Klc + swz8(krow, 4 + g));
      sacc[i] = MFMA16(aq1, bk1, sacc[i]);
    }

    // ---- online softmax (rows = wave*16 + g*4 + r; 16 lanes per row group)
    float pv[4][4];
#pragma unroll
    for (int r = 0; r < 4; ++r) {
      const int qrow = wave * 16 + g * 4 + r;
      const u32 w0 = Ml[qrow][0], w1 = Ml[qrow][1];
      float sv[4];
      u32 kp[4];
      float mx = -3e38f;
#pragma unroll
      for (int i = 0; i < 4; ++i) {
        const u32 wsel = (i < 2) ? w0 : w1;
        const u32 keep = (wsel >> (((i & 1) << 4) + l15)) & 1u;
        float s = keep ? sacc[i][r] * 0.125f : -3e38f;
        sv[i] = s;
        kp[i] = keep;
        mx = fmaxf(mx, s);
      }
#pragma unroll
      for (int off = 1; off < 16; off <<= 1) mx = fmaxf(mx, __shfl_xor(mx, off));
      const float nm = fmaxf(mrow[r], mx);
      const float sf = __expf(mrow[r] - nm);
      float ps = 0.f;
#pragma unroll
      for (int i = 0; i < 4; ++i) {
        float p = kp[i] ? __expf(sv[i] - nm) : 0.f;   // explicit 0 (nm may be -3e38)
        pv[i][r] = p;
        ps += p;
      }
#pragma unroll
      for (int off = 1; off < 16; off <<= 1) ps += __shfl_xor(ps, off);
      lrow[r] = lrow[r] * sf + ps;
      mrow[r] = nm;
      oacc[0][r] *= sf; oacc[1][r] *= sf; oacc[2][r] *= sf; oacc[3][r] *= sf;
    }

    // ---- P (C-frag layout) -> per-wave LDS tile [16 q][64 k], swizzled
    char* Pw = (char*)&Pl[wave][0];
#pragma unroll
    for (int i = 0; i < 4; ++i) {
      const int kcol = i * 16 + l15;
      const int cb = kcol >> 3, ko = kcol & 7;
#pragma unroll
      for (int r = 0; r < 4; ++r) {
        const int q = g * 4 + r;
        *(u16*)(Pw + q * 128 + ((cb ^ (q & 7)) << 4) + ko * 2) = f2bf(pv[i][r]);
      }
    }
    // same-wave DS ops are processed in order -> reads below see the writes above

    // ---- PV: ctx frag j covers hd j*16..j*16+15
#pragma unroll
    for (int ks = 0; ks < 2; ++ks) {
      bf16x8 ap = *(const bf16x8*)(Pw + swz8(l15, ks * 4 + g));
#pragma unroll
      for (int j = 0; j < 4; ++j) {
        bf16x8 bv = *(const bf16x8*)(Vlc + swz8(j * 16 + l15, ks * 4 + g));
        oacc[j] = MFMA16(ap, bv, oacc[j]);
      }
    }
  }

  // ---- epilogue: normalize, store ctx as (b*s, h*64+hd) bf16
  u16* Cb = CTX + ((size_t)(b * 2048 + q0 + wave * 16)) * 1024 + h * 64;
#pragma unroll
  for (int r = 0; r < 4; ++r) {
    const float inv = 1.0f / fmaxf(lrow[r], 1e-30f);
#pragma unroll
    for (int j = 0; j < 4; ++j) {
      Cb[(size_t)(g * 4 + r) * 1024 + j * 16 + l15] = f2bf(oacc[j][r] * inv);
    }
  }
}

// ------------------------------------------------------------------------- launch
extern "C" void kernel_launch(void* const* d_in, const int* in_sizes, int n_in,
                              void* d_out, int out_size, void* d_ws, size_t ws_size,
                              hipStream_t stream) {
  const float* x   = (const float*)d_in[0];
  const int* amask = (const int*)d_in[1];
  const float* Wq  = (const float*)d_in[2];
  const float* Wk  = (const float*)d_in[3];
  const float* Wv  = (const float*)d_in[4];
  const float* Wo  = (const float*)d_in[5];
  const float* bo  = (const float*)d_in[6];

  // workspace layout (needs ~51.4 MB)
  char* ws = (char*)d_ws;
  u16* xbf  = (u16*)(ws);                       // 8,388,608 B
  u16* wt   = (u16*)(ws + 8388608);             // 4 x 2,097,152 B (Wq^T,Wk^T,Wv^T,Wo^T bf16)
  u16* Qb   = (u16*)(ws + 16777216);            // (b,h,s,hd) bf16
  u16* Kb   = (u16*)(ws + 25165824);            // (b,h,s,hd) bf16
  u16* VT   = (u16*)(ws + 33554432);            // (b,h,hd,s) bf16
  u16* CTX  = (u16*)(ws + 41943040);            // (b*s, h*hd) bf16
  u32* MB   = (u32*)(ws + 50331648);            // 1,048,576 B bitmask

  cast_x_kernel<<<1024, 256, 0, stream>>>((const float4*)x, (ushort4*)xbf, 1048576);
  transpose_cast_kernel<<<dim3(32, 32, 4), dim3(32, 8), 0, stream>>>(Wq, Wk, Wv, Wo, wt);
  maskbits_kernel<<<1024, 256, 0, stream>>>(amask, MB);

  gemm128_kernel<0><<<dim3(32, 8), 256, 0, stream>>>(xbf, wt,            (void*)Qb, nullptr);
  gemm128_kernel<0><<<dim3(32, 8), 256, 0, stream>>>(xbf, wt + 1048576,  (void*)Kb, nullptr);
  gemm128_kernel<1><<<dim3(32, 8), 256, 0, stream>>>(xbf, wt + 2097152,  (void*)VT, nullptr);

  attn_kernel<<<dim3(32, 32), 256, 0, stream>>>(Qb, Kb, VT, MB, CTX);

  gemm128_kernel<2><<<dim3(32, 8), 256, 0, stream>>>(CTX, wt + 3145728, d_out, bo);
}

// Round 2
// 162.031 us; speedup vs baseline: 1.3905x; 1.3905x over previous
//
#include <hip/hip_runtime.h>
#include <stdint.h>

// Problem constants: B=2, S=2048, D=1024, H=16, HD=64
typedef unsigned short u16;
typedef unsigned int u32;
typedef __attribute__((ext_vector_type(8))) short bf16x8;   // 8 bf16 = 4 VGPR
typedef __attribute__((ext_vector_type(4))) float f32x4;

#define MFMA16(a, b, c) __builtin_amdgcn_mfma_f32_16x16x32_bf16((a), (b), (c), 0, 0, 0)

// 0.125 (1/sqrt(HD)) * log2(e): folded into Q so softmax runs in exp2 domain
#define QSCALE 0.18033688011112042f

__device__ __forceinline__ u16 f2bf(float f) {  // round-to-nearest-even f32->bf16
  u32 u = __float_as_uint(f);
  u += 0x7fffu + ((u >> 16) & 1u);
  return (u16)(u >> 16);
}

__device__ __forceinline__ u32 cvt_pk_bf16(float a, float b) {  // lo=bf16(a), hi=bf16(b), RNE
  u32 r;
  asm("v_cvt_pk_bf16_f32 %0, %1, %2" : "=v"(r) : "v"(a), "v"(b));
  return r;
}

// XOR swizzles (bijective within each row) to spread ds_read_b128 across banks.
__device__ __forceinline__ int swz4(int row, int cb) {   // [*][32]-elem tiles, 64B rows
  return row * 64 + ((cb ^ ((row >> 1) & 3)) << 4);
}
__device__ __forceinline__ int swz8(int row, int cb) {   // [*][64]-elem tiles, 128B rows
  return row * 128 + ((cb ^ (row & 7)) << 4);
}

// ---------------------------------------------------------------- cast x -> bf16
__global__ void cast_x_kernel(const float4* __restrict__ in, ushort4* __restrict__ out, int n4) {
  for (int i = blockIdx.x * blockDim.x + threadIdx.x; i < n4; i += gridDim.x * blockDim.x) {
    float4 v = in[i];
    ushort4 o;
    o.x = f2bf(v.x); o.y = f2bf(v.y); o.z = f2bf(v.z); o.w = f2bf(v.w);
    out[i] = o;
  }
}

// ------------------------------------------------- transpose-cast W (D x D) -> W^T bf16
__global__ void transpose_cast_kernel(const float* __restrict__ W0, const float* __restrict__ W1,
                                      const float* __restrict__ W2, const float* __restrict__ W3,
                                      u16* __restrict__ out) {
  const float* W = (blockIdx.z == 0) ? W0 : (blockIdx.z == 1) ? W1 : (blockIdx.z == 2) ? W2 : W3;
  u16* o = out + (size_t)blockIdx.z * 1048576;
  __shared__ float t[32][33];
  int tx = threadIdx.x, ty = threadIdx.y;           // (32, 8)
  int bx = blockIdx.x * 32, by = blockIdx.y * 32;
#pragma unroll
  for (int j = 0; j < 32; j += 8) t[ty + j][tx] = W[(size_t)(by + ty + j) * 1024 + bx + tx];
  __syncthreads();
#pragma unroll
  for (int j = 0; j < 32; j += 8) o[(size_t)(bx + ty + j) * 1024 + by + tx] = f2bf(t[tx][ty + j]);
}

// ------------------------------------------------------------- mask -> bitmask
__global__ void maskbits_kernel(const int* __restrict__ mask, u32* __restrict__ MB) {
  int tid = blockIdx.x * blockDim.x + threadIdx.x;
  int wid = tid >> 6, lane = tid & 63;
  int nw = (gridDim.x * blockDim.x) >> 6;
  for (int c = wid; c < 131072; c += nw) {               // B*S*S/64 chunks
    size_t base = ((size_t)(c >> 5)) * 2048 + (size_t)(c & 31) * 64;
    int v = mask[base + lane];
    unsigned long long bal = __ballot(v != 0);
    if (lane == 0) {
      MB[(size_t)c * 2]     = (u32)bal;
      MB[(size_t)c * 2 + 1] = (u32)(bal >> 32);
    }
  }
}

// ------------------------------------------------------- fused QKV GEMM (N = 3072)
// A: (4096 x 1024) bf16.  Bt: concatenated [Wq^T;Wk^T;Wv^T] (3072 rows x 1024) bf16.
// which = n/1024: 0 -> Q (scaled by QSCALE, layout (bh,s,hd)); 1 -> K (layout (bh,s,hd));
// 2 -> V (layout (bh,hd,s), packed b64 stores).
__global__ __launch_bounds__(256) void gemm_qkv_kernel(const u16* __restrict__ A,
                                                       const u16* __restrict__ Bt,
                                                       u16* __restrict__ Qo,
                                                       u16* __restrict__ Ko,
                                                       u16* __restrict__ Vo) {
  __shared__ u16 As[128 * 32];
  __shared__ u16 Bs[128 * 32];
  const int tid = threadIdx.x;
  const int lane = tid & 63;
  const int l15 = lane & 15, g = lane >> 4;
  const int wave = tid >> 6;
  const int wr = wave >> 1, wc = wave & 1;
  const int m0 = blockIdx.x * 128, n0 = blockIdx.y * 128;
  const int r0 = tid >> 2, cb0 = tid & 3;
  const int r1 = 64 + r0;
  const char* Ab = (const char*)A;
  const char* Bb = (const char*)Bt;
  char* Asc = (char*)As;
  char* Bsc = (char*)Bs;

  f32x4 acc[4][4] = {};

  for (int kt = 0; kt < 32; ++kt) {
    const int kbyte = kt * 64;
    bf16x8 ga0 = *(const bf16x8*)(Ab + (size_t)(m0 + r0) * 2048 + kbyte + cb0 * 16);
    bf16x8 ga1 = *(const bf16x8*)(Ab + (size_t)(m0 + r1) * 2048 + kbyte + cb0 * 16);
    bf16x8 gb0 = *(const bf16x8*)(Bb + (size_t)(n0 + r0) * 2048 + kbyte + cb0 * 16);
    bf16x8 gb1 = *(const bf16x8*)(Bb + (size_t)(n0 + r1) * 2048 + kbyte + cb0 * 16);
    __syncthreads();
    *(bf16x8*)(Asc + swz4(r0, cb0)) = ga0;
    *(bf16x8*)(Asc + swz4(r1, cb0)) = ga1;
    *(bf16x8*)(Bsc + swz4(r0, cb0)) = gb0;
    *(bf16x8*)(Bsc + swz4(r1, cb0)) = gb1;
    __syncthreads();

    bf16x8 af[4], bfr[4];
#pragma unroll
    for (int i = 0; i < 4; ++i)
      af[i] = *(const bf16x8*)(Asc + swz4(wr * 64 + i * 16 + l15, g));
#pragma unroll
    for (int j = 0; j < 4; ++j)
      bfr[j] = *(const bf16x8*)(Bsc + swz4(wc * 64 + j * 16 + l15, g));
#pragma unroll
    for (int i = 0; i < 4; ++i)
#pragma unroll
      for (int j = 0; j < 4; ++j)
        acc[i][j] = MFMA16(af[i], bfr[j], acc[i][j]);
  }

  const int which = n0 >> 10;                 // uniform per block
  const float scale = (which == 0) ? QSCALE : 1.0f;
  u16* outp = (which == 0) ? Qo : (which == 1) ? Ko : Vo;

#pragma unroll
  for (int i = 0; i < 4; ++i) {
    const int mrow = m0 + wr * 64 + i * 16 + g * 4;
    const int bb = mrow >> 11, s = mrow & 2047;   // same for r=0..3 (mrow multiple of 4)
#pragma unroll
    for (int j = 0; j < 4; ++j) {
      const int colg = n0 + wc * 64 + j * 16 + l15;
      const int col = colg & 1023;
      const int h = col >> 6, hd = col & 63;
      f32x4 v = acc[i][j];
      if (which == 2) {
        u32 w0 = cvt_pk_bf16(v[0], v[1]);
        u32 w1 = cvt_pk_bf16(v[2], v[3]);
        *(uint2*)(outp + ((((size_t)(bb * 16 + h)) * 64 + hd) * 2048 + s)) = make_uint2(w0, w1);
      } else {
#pragma unroll
        for (int r = 0; r < 4; ++r)
          outp[(((size_t)(bb * 16 + h)) * 2048 + s + r) * 64 + hd] = f2bf(v[r] * scale);
      }
    }
  }
}

// ---------------------------------------------------- output projection GEMM (f32 + bias)
__global__ __launch_bounds__(256) void gemm_out_kernel(const u16* __restrict__ A,
                                                       const u16* __restrict__ Bt,
                                                       float* __restrict__ outp,
                                                       const float* __restrict__ bias) {
  __shared__ u16 As[128 * 32];
  __shared__ u16 Bs[128 * 32];
  const int tid = threadIdx.x;
  const int lane = tid & 63;
  const int l15 = lane & 15, g = lane >> 4;
  const int wave = tid >> 6;
  const int wr = wave >> 1, wc = wave & 1;
  const int m0 = blockIdx.x * 128, n0 = blockIdx.y * 128;
  const int r0 = tid >> 2, cb0 = tid & 3;
  const int r1 = 64 + r0;
  const char* Ab = (const char*)A;
  const char* Bb = (const char*)Bt;
  char* Asc = (char*)As;
  char* Bsc = (char*)Bs;

  f32x4 acc[4][4] = {};

  for (int kt = 0; kt < 32; ++kt) {
    const int kbyte = kt * 64;
    bf16x8 ga0 = *(const bf16x8*)(Ab + (size_t)(m0 + r0) * 2048 + kbyte + cb0 * 16);
    bf16x8 ga1 = *(const bf16x8*)(Ab + (size_t)(m0 + r1) * 2048 + kbyte + cb0 * 16);
    bf16x8 gb0 = *(const bf16x8*)(Bb + (size_t)(n0 + r0) * 2048 + kbyte + cb0 * 16);
    bf16x8 gb1 = *(const bf16x8*)(Bb + (size_t)(n0 + r1) * 2048 + kbyte + cb0 * 16);
    __syncthreads();
    *(bf16x8*)(Asc + swz4(r0, cb0)) = ga0;
    *(bf16x8*)(Asc + swz4(r1, cb0)) = ga1;
    *(bf16x8*)(Bsc + swz4(r0, cb0)) = gb0;
    *(bf16x8*)(Bsc + swz4(r1, cb0)) = gb1;
    __syncthreads();

    bf16x8 af[4], bfr[4];
#pragma unroll
    for (int i = 0; i < 4; ++i)
      af[i] = *(const bf16x8*)(Asc + swz4(wr * 64 + i * 16 + l15, g));
#pragma unroll
    for (int j = 0; j < 4; ++j)
      bfr[j] = *(const bf16x8*)(Bsc + swz4(wc * 64 + j * 16 + l15, g));
#pragma unroll
    for (int i = 0; i < 4; ++i)
#pragma unroll
      for (int j = 0; j < 4; ++j)
        acc[i][j] = MFMA16(af[i], bfr[j], acc[i][j]);
  }

#pragma unroll
  for (int i = 0; i < 4; ++i) {
    const int mrow = m0 + wr * 64 + i * 16 + g * 4;
#pragma unroll
    for (int j = 0; j < 4; ++j) {
      const int col = n0 + wc * 64 + j * 16 + l15;
      f32x4 v = acc[i][j];
#pragma unroll
      for (int r = 0; r < 4; ++r)
        outp[(size_t)(mrow + r) * 1024 + col] = v[r] + bias[col];
    }
  }
}

// ---------------------------------------------------------------- flash attention
// grid (16 q-blocks of 128 rows, 32 bh). 512 thr = 8 waves, each wave owns 16 q-rows.
// SWAPPED operands: QK^T computed as mfma(K, Q) -> lane owns q = lane&15, holds 16 k-vals.
// PV computed as mfma(V^T, P) -> lane's ctx outputs share the same q = lane&15.
// Q pre-scaled by QSCALE -> softmax in exp2 domain. T13 defer-max (THR=8). 1 barrier/iter.
__global__ __launch_bounds__(512, 4) void attn_kernel(const u16* __restrict__ Q,
                                                      const u16* __restrict__ K,
                                                      const u16* __restrict__ VT,
                                                      const u32* __restrict__ MB,
                                                      u16* __restrict__ CTX) {
  __shared__ u16 Kl[2][4096];     // [64 k][64 hd], swizzled
  __shared__ u16 Vl[2][4096];     // [64 hd][64 k], swizzled
  __shared__ u16 Pl[8][1024];     // per-wave [16 q][64 k], swizzled
  const int tid = threadIdx.x, lane = tid & 63, wave = tid >> 6;
  const int l15 = lane & 15, g = lane >> 4;
  const int q0 = blockIdx.x * 128, bh = blockIdx.y;
  const int b = bh >> 4, h = bh & 15;
  const int sr = tid >> 3, scb = tid & 7;   // staging coords: 64 rows x 8 chunks

  // Q fragments (B operand): col=q=l15, k-chunk g
  const char* Qb = (const char*)Q + ((size_t)bh * 2048 + q0 + wave * 16) * 128;
  bf16x8 aq0 = *(const bf16x8*)(Qb + l15 * 128 + g * 16);
  bf16x8 aq1 = *(const bf16x8*)(Qb + l15 * 128 + 64 + g * 16);

  const char* Kg = (const char*)K + (size_t)bh * 2048 * 128;
  const char* Vg = (const char*)VT + (size_t)bh * 64 * 4096;
  const u32* mp = MB + ((size_t)b * 2048 + q0 + wave * 16 + l15) * 64;
  char* Pw = (char*)&Pl[wave][0];

  f32x4 oacc[4] = {};
  float mrow = -1e30f, lrow = 0.f;

  // prologue: stage kb=0
  {
    bf16x8 kreg = *(const bf16x8*)(Kg + (size_t)sr * 128 + scb * 16);
    bf16x8 vreg = *(const bf16x8*)(Vg + (size_t)sr * 4096 + scb * 16);
    *(bf16x8*)((char*)&Kl[0][0] + swz8(sr, scb)) = kreg;
    *(bf16x8*)((char*)&Vl[0][0] + swz8(sr, scb)) = vreg;
  }
  uint2 mcur = *(const uint2*)mp;
  __syncthreads();

  int cur = 0;
  for (int kb = 0; kb < 32; ++kb) {
    const int kn = (kb < 31) ? kb + 1 : 31;
    // T14: issue next-tile loads now, consume (ds_write) after compute
    bf16x8 kreg = *(const bf16x8*)(Kg + (size_t)(kn * 64 + sr) * 128 + scb * 16);
    bf16x8 vreg = *(const bf16x8*)(Vg + (size_t)sr * 4096 + kn * 128 + scb * 16);
    uint2 mnext = *(const uint2*)(mp + (size_t)kn * 2);

    const char* Kc = (const char*)&Kl[cur][0];
    const char* Vc = (const char*)&Vl[cur][0];

    // ---- S^T = K Q^T: frag i rows = k i*16..i*16+15, cols = q
    f32x4 sacc[4] = {};
#pragma unroll
    for (int i = 0; i < 4; ++i) {
      const int krow = i * 16 + l15;
      bf16x8 bk0 = *(const bf16x8*)(Kc + swz8(krow, g));
      sacc[i] = MFMA16(bk0, aq0, sacc[i]);
      bf16x8 bk1 = *(const bf16x8*)(Kc + swz8(krow, 4 + g));
      sacc[i] = MFMA16(bk1, aq1, sacc[i]);
    }

    // ---- mask select in place: lane's k = i*16 + g*4 + r, q = l15
#pragma unroll
    for (int i = 0; i < 4; ++i) {
      const u32 wsel = (i & 2) ? mcur.y : mcur.x;
      const u32 wi = wsel >> ((i & 1) * 16 + g * 4);
#pragma unroll
      for (int r = 0; r < 4; ++r)
        sacc[i][r] = (wi & (1u << r)) ? sacc[i][r] : -3e38f;
    }

    // ---- row max: in-lane tree (16 vals) + 2 cross-group shuffles
    float m0v = fmaxf(fmaxf(sacc[0][0], sacc[0][1]), fmaxf(sacc[0][2], sacc[0][3]));
    float m1v = fmaxf(fmaxf(sacc[1][0], sacc[1][1]), fmaxf(sacc[1][2], sacc[1][3]));
    float m2v = fmaxf(fmaxf(sacc[2][0], sacc[2][1]), fmaxf(sacc[2][2], sacc[2][3]));
    float m3v = fmaxf(fmaxf(sacc[3][0], sacc[3][1]), fmaxf(sacc[3][2], sacc[3][3]));
    float mx = fmaxf(fmaxf(m0v, m1v), fmaxf(m2v, m3v));
    mx = fmaxf(mx, __shfl_xor(mx, 16));
    mx = fmaxf(mx, __shfl_xor(mx, 32));

    // ---- T13 defer-max: only rescale when max grew by > 8 (p bounded by 2^8)
    if (__any(mx > mrow + 8.0f)) {
      const float nm = fmaxf(mrow, mx);
      const float sf = __builtin_amdgcn_exp2f(mrow - nm);
      lrow *= sf;
#pragma unroll
      for (int j = 0; j < 4; ++j) {
        oacc[j][0] *= sf; oacc[j][1] *= sf; oacc[j][2] *= sf; oacc[j][3] *= sf;
      }
      mrow = nm;
    }

    // ---- p = exp2(s - m), pack to bf16, per-wave P tile write (b64, k-contiguous)
    float psum[4];
#pragma unroll
    for (int i = 0; i < 4; ++i) {
      float p0 = __builtin_amdgcn_exp2f(sacc[i][0] - mrow);
      float p1 = __builtin_amdgcn_exp2f(sacc[i][1] - mrow);
      float p2 = __builtin_amdgcn_exp2f(sacc[i][2] - mrow);
      float p3 = __builtin_amdgcn_exp2f(sacc[i][3] - mrow);
      psum[i] = (p0 + p1) + (p2 + p3);
      u32 w0 = cvt_pk_bf16(p0, p1);
      u32 w1 = cvt_pk_bf16(p2, p3);
      const int cb = i * 2 + (g >> 1);
      *(uint2*)(Pw + l15 * 128 + ((cb ^ (l15 & 7)) << 4) + (g & 1) * 8) = make_uint2(w0, w1);
    }
    float ps = (psum[0] + psum[1]) + (psum[2] + psum[3]);
    ps += __shfl_xor(ps, 16);
    ps += __shfl_xor(ps, 32);
    lrow += ps;

    // ---- ctx^T += V^T P^T: frag j rows = hd j*16.., cols = q (same-wave DS ordered)
#pragma unroll
    for (int ks = 0; ks < 2; ++ks) {
      bf16x8 ap = *(const bf16x8*)(Pw + swz8(l15, ks * 4 + g));
#pragma unroll
      for (int j = 0; j < 4; ++j) {
        bf16x8 bv = *(const bf16x8*)(Vc + swz8(j * 16 + l15, ks * 4 + g));
        oacc[j] = MFMA16(bv, ap, oacc[j]);
      }
    }

    // ---- write next tile into other buffer, single barrier
    char* Kd = (char*)&Kl[cur ^ 1][0];
    char* Vd = (char*)&Vl[cur ^ 1][0];
    *(bf16x8*)(Kd + swz8(sr, scb)) = kreg;
    *(bf16x8*)(Vd + swz8(sr, scb)) = vreg;
    __syncthreads();
    cur ^= 1;
    mcur = mnext;
  }

  // ---- epilogue: normalize (q = l15 in-lane), packed b64 stores
  const float inv = 1.0f / fmaxf(lrow, 1e-30f);
  u16* Cb = CTX + ((size_t)(b * 2048 + q0 + wave * 16 + l15)) * 1024 + h * 64 + g * 4;
#pragma unroll
  for (int j = 0; j < 4; ++j) {
    u32 w0 = cvt_pk_bf16(oacc[j][0] * inv, oacc[j][1] * inv);
    u32 w1 = cvt_pk_bf16(oacc[j][2] * inv, oacc[j][3] * inv);
    *(uint2*)(Cb + j * 16) = make_uint2(w0, w1);
  }
}

// ------------------------------------------------------------------------- launch
extern "C" void kernel_launch(void* const* d_in, const int* in_sizes, int n_in,
                              void* d_out, int out_size, void* d_ws, size_t ws_size,
                              hipStream_t stream) {
  const float* x   = (const float*)d_in[0];
  const int* amask = (const int*)d_in[1];
  const float* Wq  = (const float*)d_in[2];
  const float* Wk  = (const float*)d_in[3];
  const float* Wv  = (const float*)d_in[4];
  const float* Wo  = (const float*)d_in[5];
  const float* bo  = (const float*)d_in[6];

  // workspace layout (~51.4 MB)
  char* ws = (char*)d_ws;
  u16* xbf  = (u16*)(ws);                       // 8,388,608 B
  u16* wt   = (u16*)(ws + 8388608);             // 4 x 2,097,152 B (Wq^T,Wk^T,Wv^T,Wo^T bf16)
  u16* Qb   = (u16*)(ws + 16777216);            // (b,h,s,hd) bf16 (pre-scaled by QSCALE)
  u16* Kb   = (u16*)(ws + 25165824);            // (b,h,s,hd) bf16
  u16* VT   = (u16*)(ws + 33554432);            // (b,h,hd,s) bf16
  u16* CTX  = (u16*)(ws + 41943040);            // (b*s, h*hd) bf16
  u32* MB   = (u32*)(ws + 50331648);            // 1,048,576 B bitmask

  cast_x_kernel<<<1024, 256, 0, stream>>>((const float4*)x, (ushort4*)xbf, 1048576);
  transpose_cast_kernel<<<dim3(32, 32, 4), dim3(32, 8), 0, stream>>>(Wq, Wk, Wv, Wo, wt);
  maskbits_kernel<<<1024, 256, 0, stream>>>(amask, MB);

  gemm_qkv_kernel<<<dim3(32, 24), 256, 0, stream>>>(xbf, wt, Qb, Kb, VT);

  attn_kernel<<<dim3(16, 32), 512, 0, stream>>>(Qb, Kb, VT, MB, CTX);

  gemm_out_kernel<<<dim3(32, 8), 256, 0, stream>>>(CTX, wt + 3145728, (float*)d_out, bo);
}

// Round 3
// 157.592 us; speedup vs baseline: 1.4297x; 1.0282x over previous
//
#include <hip/hip_runtime.h>
#include <stdint.h>

// Problem constants: B=2, S=2048, D=1024, H=16, HD=64
typedef unsigned short u16;
typedef unsigned int u32;
typedef __attribute__((ext_vector_type(8))) short bf16x8;   // 8 bf16 = 4 VGPR
typedef __attribute__((ext_vector_type(4))) float f32x4;
typedef __attribute__((ext_vector_type(4))) u32 u32x4;

#define MFMA16(a, b, c) __builtin_amdgcn_mfma_f32_16x16x32_bf16((a), (b), (c), 0, 0, 0)

// 0.125 (1/sqrt(HD)) * log2(e): folded into Q so softmax runs in exp2 domain
#define QSCALE 0.18033688011112042f

__device__ __forceinline__ u16 f2bf(float f) {  // round-to-nearest-even f32->bf16
  u32 u = __float_as_uint(f);
  u += 0x7fffu + ((u >> 16) & 1u);
  return (u16)(u >> 16);
}

__device__ __forceinline__ u32 cvt_pk_bf16(float a, float b) {  // lo=bf16(a), hi=bf16(b)
  u32 r;
  asm("v_cvt_pk_bf16_f32 %0, %1, %2" : "=v"(r) : "v"(a), "v"(b));
  return r;
}

__device__ __forceinline__ void load_lds16(const void* g, void* l) {
  __builtin_amdgcn_global_load_lds((const __attribute__((address_space(1))) void*)g,
                                   (__attribute__((address_space(3))) void*)l, 16, 0, 0);
}

// XOR swizzle for [*][64]-elem (128B-row) tiles
__device__ __forceinline__ int swz8(int row, int cb) {
  return row * 128 + ((cb ^ (row & 7)) << 4);
}

// ----------------------------------------------- fused prep: cast x, transpose W, mask bits
__global__ __launch_bounds__(256) void prep_kernel(const float4* __restrict__ x,
                                                   const int* __restrict__ mask,
                                                   const float* __restrict__ W0,
                                                   const float* __restrict__ W1,
                                                   const float* __restrict__ W2,
                                                   const float* __restrict__ W3,
                                                   ushort4* __restrict__ xbf,
                                                   u16* __restrict__ wt,
                                                   u32* __restrict__ MB) {
  const int bid = blockIdx.x, tid = threadIdx.x;
  __shared__ float t[32][33];
  if (bid < 1024) {
    // cast x -> bf16 (1,048,576 float4)
    for (int i = bid * 256 + tid; i < 1048576; i += 262144) {
      float4 v = x[i];
      ushort4 o;
      o.x = f2bf(v.x); o.y = f2bf(v.y); o.z = f2bf(v.z); o.w = f2bf(v.w);
      xbf[i] = o;
    }
  } else if (bid < 5120) {
    // transpose-cast the four weight matrices
    int r = bid - 1024;
    const int z = r >> 10; r &= 1023;
    const int by = (r >> 5) << 5, bx = (r & 31) << 5;
    const float* W = (z == 0) ? W0 : (z == 1) ? W1 : (z == 2) ? W2 : W3;
    u16* o = wt + (size_t)z * 1048576;
    const int tx = tid & 31, ty = tid >> 5;   // (32, 8)
#pragma unroll
    for (int j = 0; j < 32; j += 8) t[ty + j][tx] = W[(size_t)(by + ty + j) * 1024 + bx + tx];
    __syncthreads();
#pragma unroll
    for (int j = 0; j < 32; j += 8) o[(size_t)(bx + ty + j) * 1024 + by + tx] = f2bf(t[tx][ty + j]);
  } else {
    // mask -> bitmask. MB[(b*2048+q)*64 + w] covers k = w*32..w*32+31
    const int gtid = (bid - 5120) * 256 + tid;
    const int wid = gtid >> 6, lane = gtid & 63;
    for (int c = wid; c < 131072; c += 4096) {
      size_t base = ((size_t)(c >> 5)) * 2048 + (size_t)(c & 31) * 64;
      int v = mask[base + lane];
      unsigned long long bal = __ballot(v != 0);
      if (lane == 0) {
        MB[(size_t)c * 2]     = (u32)bal;
        MB[(size_t)c * 2 + 1] = (u32)(bal >> 32);
      }
    }
  }
}

// ------------------------------------------------------------------ GEMM (m97 structure)
// 128x128 tile, BK=32, linear LDS, global_load_lds(16) staging, 2-barrier loop.
// MODE 0: fused QKV (Bt = [Wq^T;Wk^T;Wv^T], N=3072) -> Q(scaled)/K at (bh,s,hd), V^T at (bh,hd,s)
// MODE 1: output projection -> f32 row-major + bias
template <int MODE>
__global__ __launch_bounds__(256) void gemm_kernel(const u16* __restrict__ A,
                                                   const u16* __restrict__ Bt,
                                                   u16* __restrict__ Qo, u16* __restrict__ Ko,
                                                   u16* __restrict__ Vo, float* __restrict__ Fo,
                                                   const float* __restrict__ bias) {
  __shared__ u16 As[4096];
  __shared__ u16 Bs[4096];
  const int tid = threadIdx.x, lane = tid & 63;
  const int l15 = lane & 15, g = lane >> 4;
  const int wave = tid >> 6, wr = wave >> 1, wc = wave & 1;
  const int m0 = blockIdx.x * 128, n0 = blockIdx.y * 128;
  const int srow = tid >> 2, scb = tid & 3;
  const char* Ab = (const char*)A + (size_t)(m0 + srow) * 2048 + scb * 16;
  const char* Bb = (const char*)Bt + (size_t)(n0 + srow) * 2048 + scb * 16;
  char* Asc = (char*)As;
  char* Bsc = (char*)Bs;
  char* ldsA = Asc + wave * 1024;   // wave-uniform dest base (+ lane*16 by HW)
  char* ldsB = Bsc + wave * 1024;

  f32x4 acc[4][4] = {};

  for (int kt = 0; kt < 32; ++kt) {
    const int kbyte = kt * 64;
    __syncthreads();                       // previous iteration's LDS reads done
    load_lds16(Ab + kbyte, ldsA);
    load_lds16(Ab + kbyte + (size_t)64 * 2048, ldsA + 4096);
    load_lds16(Bb + kbyte, ldsB);
    load_lds16(Bb + kbyte + (size_t)64 * 2048, ldsB + 4096);
    __syncthreads();                       // implies vmcnt(0): staged data visible

    bf16x8 af[4], bfr[4];
#pragma unroll
    for (int i = 0; i < 4; ++i)
      af[i] = *(const bf16x8*)(Asc + (wr * 64 + i * 16 + l15) * 64 + g * 16);
#pragma unroll
    for (int j = 0; j < 4; ++j)
      bfr[j] = *(const bf16x8*)(Bsc + (wc * 64 + j * 16 + l15) * 64 + g * 16);
#pragma unroll
    for (int i = 0; i < 4; ++i)
#pragma unroll
      for (int j = 0; j < 4; ++j)
        acc[i][j] = MFMA16(af[i], bfr[j], acc[i][j]);
  }

  // epilogue. C frag: col = lane&15, row = (lane>>4)*4 + r
  if (MODE == 1) {
#pragma unroll
    for (int i = 0; i < 4; ++i) {
      const int mrow = m0 + wr * 64 + i * 16 + g * 4;
#pragma unroll
      for (int j = 0; j < 4; ++j) {
        const int col = n0 + wc * 64 + j * 16 + l15;
        f32x4 v = acc[i][j];
#pragma unroll
        for (int r = 0; r < 4; ++r)
          Fo[(size_t)(mrow + r) * 1024 + col] = v[r] + bias[col];
      }
    }
  } else {
    const int which = n0 >> 10;                 // uniform per block
    const float scale = (which == 0) ? QSCALE : 1.0f;
    u16* outp = (which == 0) ? Qo : (which == 1) ? Ko : Vo;
#pragma unroll
    for (int i = 0; i < 4; ++i) {
      const int mrow = m0 + wr * 64 + i * 16 + g * 4;
      const int bb = mrow >> 11, s = mrow & 2047;
#pragma unroll
      for (int j = 0; j < 4; ++j) {
        const int col = (n0 + wc * 64 + j * 16 + l15) & 1023;
        const int h = col >> 6, hd = col & 63;
        f32x4 v = acc[i][j];
        if (which == 2) {
          u32 w0 = cvt_pk_bf16(v[0], v[1]);
          u32 w1 = cvt_pk_bf16(v[2], v[3]);
          *(uint2*)(outp + ((((size_t)(bb * 16 + h)) * 64 + hd) * 2048 + s)) = make_uint2(w0, w1);
        } else {
#pragma unroll
          for (int r = 0; r < 4; ++r)
            outp[(((size_t)(bb * 16 + h)) * 2048 + s + r) * 64 + hd] = f2bf(v[r] * scale);
        }
      }
    }
  }
}

// ---------------------------------------------------------------- flash attention
// grid (16 q-blocks of 128 rows, 32 bh). 256 thr = 4 waves, each wave owns 32 q-rows
// (2 q-frags/lane). Swapped operands: lane owns q = l15 (frag0) and 16+l15 (frag1).
// P stays IN REGISTERS: the V LDS tile's k-columns are permuted so each lane's owned
// packed P words are exactly the PV B-frag k-slices (no P exchange, no P LDS).
// V tile chunk layout (per 64-k tile): chunk c (c<4) = [k-quad c | k-quad c+4];
//                                      chunk 4+c     = [k-quad 8+c | k-quad 12+c].
__global__ __launch_bounds__(256, 2) void attn_kernel(const u16* __restrict__ Q,
                                                      const u16* __restrict__ K,
                                                      const u16* __restrict__ VT,
                                                      const u32* __restrict__ MB,
                                                      u16* __restrict__ CTX) {
  __shared__ u16 Kl[2][4096];     // [64 k][64 hd], swizzled rows
  __shared__ u16 Vl[2][4096];     // [64 hd][64 k], k-permuted chunks + swizzled rows
  const int tid = threadIdx.x, lane = tid & 63, wave = tid >> 6;
  const int l15 = lane & 15, g = lane >> 4;
  const int q0 = blockIdx.x * 128, bh = blockIdx.y;
  const int b = bh >> 4, h = bh & 15;
  const int qw0 = q0 + wave * 32;

  // Q fragments (B operand of mfma(K,Q)): col=q, k-slice = hd 8g..8g+7 (+32 for kk=1)
  const char* Qb = (const char*)Q + ((size_t)bh * 2048 + qw0) * 128;
  const bf16x8 aq00 = *(const bf16x8*)(Qb + l15 * 128 + g * 16);
  const bf16x8 aq01 = *(const bf16x8*)(Qb + l15 * 128 + 64 + g * 16);
  const bf16x8 aq10 = *(const bf16x8*)(Qb + (16 + l15) * 128 + g * 16);
  const bf16x8 aq11 = *(const bf16x8*)(Qb + (16 + l15) * 128 + 64 + g * 16);

  const char* Kg = (const char*)K + (size_t)bh * 2048 * 128;
  const char* Vg = (const char*)VT + (size_t)bh * 64 * 4096;
  const u32* mp0 = MB + ((size_t)b * 2048 + qw0 + l15) * 64;
  const u32* mp1 = mp0 + 16 * 64;

  // staging: slot s in {tid, tid+256}: row = s>>3 (0..63), 16B-chunk = s&7
  const int sr = tid >> 3, scb = tid & 7;
  // V permuted-write targets for the two k-quads of this thread's b128:
  const int vc0 = 2 * (scb & 1) + (scb & 4);  // chunk of quad t0=2*scb (t1 -> vc0+1)
  const int vh = (scb >> 1) & 1;              // 8B half

  f32x4 oacc[4][2] = {};                       // [hd-frag j][q-frag f]
  float mrow[2] = {-1e30f, -1e30f}, lrow[2] = {0.f, 0.f};

  // prologue: stage kb=0
  {
    bf16x8 k0 = *(const bf16x8*)(Kg + (size_t)sr * 128 + scb * 16);
    bf16x8 k1 = *(const bf16x8*)(Kg + (size_t)(32 + sr) * 128 + scb * 16);
    bf16x8 v0 = *(const bf16x8*)(Vg + (size_t)sr * 4096 + scb * 16);
    bf16x8 v1 = *(const bf16x8*)(Vg + (size_t)(32 + sr) * 4096 + scb * 16);
    *(bf16x8*)((char*)Kl[0] + swz8(sr, scb)) = k0;
    *(bf16x8*)((char*)Kl[0] + swz8(32 + sr, scb)) = k1;
    uint4 u0 = __builtin_bit_cast(uint4, v0);
    uint4 u1 = __builtin_bit_cast(uint4, v1);
    char* vb0 = (char*)Vl[0] + sr * 128 + vh * 8;
    char* vb1 = (char*)Vl[0] + (32 + sr) * 128 + vh * 8;
    *(uint2*)(vb0 + ((vc0 ^ (sr & 7)) << 4)) = make_uint2(u0.x, u0.y);
    *(uint2*)(vb0 + (((vc0 + 1) ^ (sr & 7)) << 4)) = make_uint2(u0.z, u0.w);
    *(uint2*)(vb1 + ((vc0 ^ ((32 + sr) & 7)) << 4)) = make_uint2(u1.x, u1.y);
    *(uint2*)(vb1 + (((vc0 + 1) ^ ((32 + sr) & 7)) << 4)) = make_uint2(u1.z, u1.w);
  }
  uint2 mcA = *(const uint2*)mp0;
  uint2 mcB = *(const uint2*)mp1;
  __syncthreads();

  int cur = 0;
  for (int kb = 0; kb < 32; ++kb) {
    const int kn = (kb < 31) ? kb + 1 : 31;
    // T14: issue next-tile loads now, ds_write them after compute
    bf16x8 k0 = *(const bf16x8*)(Kg + (size_t)(kn * 64 + sr) * 128 + scb * 16);
    bf16x8 k1 = *(const bf16x8*)(Kg + (size_t)(kn * 64 + 32 + sr) * 128 + scb * 16);
    bf16x8 v0 = *(const bf16x8*)(Vg + (size_t)sr * 4096 + kn * 128 + scb * 16);
    bf16x8 v1 = *(const bf16x8*)(Vg + (size_t)(32 + sr) * 4096 + kn * 128 + scb * 16);
    uint2 mn0 = *(const uint2*)(mp0 + (size_t)kn * 2);
    uint2 mn1 = *(const uint2*)(mp1 + (size_t)kn * 2);

    const char* Kc = (const char*)Kl[cur];
    const char* Vc = (const char*)Vl[cur];

    // ---- S^T = K Q^T for both q-frags: lane's element (q = f*16+l15, k = 16i+4g+r)
    f32x4 sa[2][4];
#pragma unroll
    for (int i = 0; i < 4; ++i) {
      const int kr = i * 16 + l15;
      bf16x8 bk0 = *(const bf16x8*)(Kc + swz8(kr, g));
      bf16x8 bk1 = *(const bf16x8*)(Kc + swz8(kr, 4 + g));
      f32x4 z = {0.f, 0.f, 0.f, 0.f};
      sa[0][i] = MFMA16(bk1, aq01, MFMA16(bk0, aq00, z));
      sa[1][i] = MFMA16(bk1, aq11, MFMA16(bk0, aq10, z));
    }

    // ---- softmax per q-frag (all in-lane + 2 shuffles)
    u32 Wp[2][8];
#pragma unroll
    for (int f = 0; f < 2; ++f) {
      const uint2 mc = (f == 0) ? mcA : mcB;
      // mask -> -3e38 (exp2 underflows to exact 0)
#pragma unroll
      for (int i = 0; i < 4; ++i) {
        const u32 wsel = (i & 2) ? mc.y : mc.x;
        const u32 wi = wsel >> ((i & 1) * 16 + g * 4);
#pragma unroll
        for (int r = 0; r < 4; ++r)
          sa[f][i][r] = (wi & (1u << r)) ? sa[f][i][r] : -3e38f;
      }
      float mx = fmaxf(
          fmaxf(fmaxf(fmaxf(sa[f][0][0], sa[f][0][1]), fmaxf(sa[f][0][2], sa[f][0][3])),
                fmaxf(fmaxf(sa[f][1][0], sa[f][1][1]), fmaxf(sa[f][1][2], sa[f][1][3]))),
          fmaxf(fmaxf(fmaxf(sa[f][2][0], sa[f][2][1]), fmaxf(sa[f][2][2], sa[f][2][3])),
                fmaxf(fmaxf(sa[f][3][0], sa[f][3][1]), fmaxf(sa[f][3][2], sa[f][3][3]))));
      mx = fmaxf(mx, __shfl_xor(mx, 16));
      mx = fmaxf(mx, __shfl_xor(mx, 32));
      // T13 defer-max: rescale only when max grew by > 8 (p bounded by 2^8)
      if (__any(mx > mrow[f] + 8.0f)) {
        const float nm = fmaxf(mrow[f], mx);
        const float sf = __builtin_amdgcn_exp2f(mrow[f] - nm);
        lrow[f] *= sf;
#pragma unroll
        for (int j = 0; j < 4; ++j) {
          oacc[j][f][0] *= sf; oacc[j][f][1] *= sf;
          oacc[j][f][2] *= sf; oacc[j][f][3] *= sf;
        }
        mrow[f] = nm;
      }
      float ps = 0.f;
#pragma unroll
      for (int i = 0; i < 4; ++i) {
        const float p0 = __builtin_amdgcn_exp2f(sa[f][i][0] - mrow[f]);
        const float p1 = __builtin_amdgcn_exp2f(sa[f][i][1] - mrow[f]);
        const float p2 = __builtin_amdgcn_exp2f(sa[f][i][2] - mrow[f]);
        const float p3 = __builtin_amdgcn_exp2f(sa[f][i][3] - mrow[f]);
        ps += (p0 + p1) + (p2 + p3);
        Wp[f][i * 2] = cvt_pk_bf16(p0, p1);
        Wp[f][i * 2 + 1] = cvt_pk_bf16(p2, p3);
      }
      ps += __shfl_xor(ps, 16);
      ps += __shfl_xor(ps, 32);
      lrow[f] += ps;
    }

    // ---- PV: ctx^T[hd][q] += V^T P^T. B-frag = lane's own words (V k-permutation).
#pragma unroll
    for (int ks = 0; ks < 2; ++ks) {
      u32x4 t0 = {Wp[0][ks * 4], Wp[0][ks * 4 + 1], Wp[0][ks * 4 + 2], Wp[0][ks * 4 + 3]};
      u32x4 t1 = {Wp[1][ks * 4], Wp[1][ks * 4 + 1], Wp[1][ks * 4 + 2], Wp[1][ks * 4 + 3]};
      const bf16x8 ap0 = __builtin_bit_cast(bf16x8, t0);
      const bf16x8 ap1 = __builtin_bit_cast(bf16x8, t1);
#pragma unroll
      for (int j = 0; j < 4; ++j) {
        bf16x8 bv = *(const bf16x8*)(Vc + swz8(j * 16 + l15, ks * 4 + g));
        oacc[j][0] = MFMA16(bv, ap0, oacc[j][0]);
        oacc[j][1] = MFMA16(bv, ap1, oacc[j][1]);
      }
    }

    // ---- write next tile into other buffer, single barrier
    {
      char* Kd = (char*)Kl[cur ^ 1];
      char* Vd = (char*)Vl[cur ^ 1];
      *(bf16x8*)(Kd + swz8(sr, scb)) = k0;
      *(bf16x8*)(Kd + swz8(32 + sr, scb)) = k1;
      uint4 u0 = __builtin_bit_cast(uint4, v0);
      uint4 u1 = __builtin_bit_cast(uint4, v1);
      char* vb0 = Vd + sr * 128 + vh * 8;
      char* vb1 = Vd + (32 + sr) * 128 + vh * 8;
      *(uint2*)(vb0 + ((vc0 ^ (sr & 7)) << 4)) = make_uint2(u0.x, u0.y);
      *(uint2*)(vb0 + (((vc0 + 1) ^ (sr & 7)) << 4)) = make_uint2(u0.z, u0.w);
      *(uint2*)(vb1 + ((vc0 ^ ((32 + sr) & 7)) << 4)) = make_uint2(u1.x, u1.y);
      *(uint2*)(vb1 + (((vc0 + 1) ^ ((32 + sr) & 7)) << 4)) = make_uint2(u1.z, u1.w);
    }
    __syncthreads();
    cur ^= 1;
    mcA = mn0;
    mcB = mn1;
  }

  // ---- epilogue: normalize, store ctx as (b*s, h*64+hd) bf16
#pragma unroll
  for (int f = 0; f < 2; ++f) {
    const float inv = 1.0f / fmaxf(lrow[f], 1e-30f);
    u16* Cb = CTX + ((size_t)(b * 2048 + qw0 + f * 16 + l15)) * 1024 + h * 64 + g * 4;
#pragma unroll
    for (int j = 0; j < 4; ++j) {
      u32 w0 = cvt_pk_bf16(oacc[j][f][0] * inv, oacc[j][f][1] * inv);
      u32 w1 = cvt_pk_bf16(oacc[j][f][2] * inv, oacc[j][f][3] * inv);
      *(uint2*)(Cb + j * 16) = make_uint2(w0, w1);
    }
  }
}

// ------------------------------------------------------------------------- launch
extern "C" void kernel_launch(void* const* d_in, const int* in_sizes, int n_in,
                              void* d_out, int out_size, void* d_ws, size_t ws_size,
                              hipStream_t stream) {
  const float* x   = (const float*)d_in[0];
  const int* amask = (const int*)d_in[1];
  const float* Wq  = (const float*)d_in[2];
  const float* Wk  = (const float*)d_in[3];
  const float* Wv  = (const float*)d_in[4];
  const float* Wo  = (const float*)d_in[5];
  const float* bo  = (const float*)d_in[6];

  // workspace layout (~51.4 MB)
  char* ws = (char*)d_ws;
  u16* xbf  = (u16*)(ws);                       // 8,388,608 B
  u16* wt   = (u16*)(ws + 8388608);             // 4 x 2,097,152 B (Wq^T,Wk^T,Wv^T,Wo^T bf16)
  u16* Qb   = (u16*)(ws + 16777216);            // (b,h,s,hd) bf16 (pre-scaled by QSCALE)
  u16* Kb   = (u16*)(ws + 25165824);            // (b,h,s,hd) bf16
  u16* VT   = (u16*)(ws + 33554432);            // (b,h,hd,s) bf16
  u16* CTX  = (u16*)(ws + 41943040);            // (b*s, h*hd) bf16
  u32* MB   = (u32*)(ws + 50331648);            // 1,048,576 B bitmask

  prep_kernel<<<6144, 256, 0, stream>>>((const float4*)x, amask, Wq, Wk, Wv, Wo,
                                        (ushort4*)xbf, wt, MB);

  gemm_kernel<0><<<dim3(32, 24), 256, 0, stream>>>(xbf, wt, Qb, Kb, VT, nullptr, nullptr);

  attn_kernel<<<dim3(16, 32), 256, 0, stream>>>(Qb, Kb, VT, MB, CTX);

  gemm_kernel<1><<<dim3(32, 8), 256, 0, stream>>>(CTX, wt + 3145728, nullptr, nullptr, nullptr,
                                                  (float*)d_out, bo);
}